// Round 5
// baseline (238.021 us; speedup 1.0000x reference)
//
#include <hip/hip_runtime.h>
#include <math.h>

#define EPS 1e-7f
#define FN_PENALTY 10.0f
#define BLOCK 256

__device__ __forceinline__ float waveReduceSum(float v) {
    #pragma unroll
    for (int off = 32; off > 0; off >>= 1)
        v += __shfl_down(v, off, 64);
    return v;
}

__device__ __forceinline__ float4 validate_fix(float4 b) {
    bool invalid = (b.x > b.z) || (b.y > b.w);
    if (invalid) {
        b.x = fmaxf(b.x, 0.0f);
        b.y = fmaxf(b.y, 0.0f);
        b.z = fmaxf(b.z, 0.0f);
        b.w = fmaxf(b.w, 0.0f);
    }
    b.z = fmaxf(b.z, b.x + 1e-6f);
    b.w = fmaxf(b.w, b.y + 1e-6f);
    return b;
}

struct Row {
    float4 lg, pb, tb;
    float  cl, ct;
    int    lbl;
};

__device__ __forceinline__ Row load_row(
    const float4* __restrict__ pred_logits,
    const int*    __restrict__ labels,
    const float4* __restrict__ pred_boxes,
    const float4* __restrict__ target_boxes,
    const float*  __restrict__ cut_logits,
    const float*  __restrict__ cut_targets,
    int i)
{
    Row r;
    r.lg  = pred_logits[i];
    r.lbl = labels[i];
    r.pb  = pred_boxes[i];
    r.tb  = target_boxes[i];
    r.cl  = cut_logits[i];
    r.ct  = cut_targets[i];
    return r;
}

__device__ __forceinline__ void accum_row(
    const Row& r,
    float& s_class, float& s_bbox, float& s_giou, float& s_cut)
{
    // ---- focal class loss ----
    float l0 = r.lg.x, l1 = r.lg.y, l2 = r.lg.z, l3 = r.lg.w;
    float m = fmaxf(fmaxf(l0, l1), fmaxf(l2, l3));
    float e0 = __expf(l0 - m), e1 = __expf(l1 - m),
          e2 = __expf(l2 - m), e3 = __expf(l3 - m);
    float se = e0 + e1 + e2 + e3;
    int lbl = r.lbl & 3;
    float esel = (lbl == 0) ? e0 : (lbl == 1) ? e1 : (lbl == 2) ? e2 : e3;
    float pt = __fdividef(esel, se);   // exp(lsel - lse)
    float ce = -__logf(pt);            // lse - lsel
    float om = 1.0f - pt;
    s_class += om * om * ce;           // ALPHA=1, GAMMA=2

    // ---- bbox L1 ----
    s_bbox += fabsf(r.pb.x - r.tb.x) + fabsf(r.pb.y - r.tb.y)
            + fabsf(r.pb.z - r.tb.z) + fabsf(r.pb.w - r.tb.w);

    // ---- GIoU ----
    float4 b1 = validate_fix(r.pb);
    float4 b2 = validate_fix(r.tb);
    float area1 = (b1.z - b1.x) * (b1.w - b1.y);
    float area2 = (b2.z - b2.x) * (b2.w - b2.y);
    float ltx = fmaxf(b1.x, b2.x), lty = fmaxf(b1.y, b2.y);
    float rbx = fminf(b1.z, b2.z), rby = fminf(b1.w, b2.w);
    float iw = fmaxf(rbx - ltx, 0.0f), ih = fmaxf(rby - lty, 0.0f);
    float inter = iw * ih;
    float uni = area1 + area2 - inter;
    float iou = __fdividef(inter, uni + EPS);
    float ex1 = fminf(b1.x, b2.x), ey1 = fminf(b1.y, b2.y);
    float ex2 = fmaxf(b1.z, b2.z), ey2 = fmaxf(b1.w, b2.w);
    float ew = fmaxf(ex2 - ex1, 0.0f), eh = fmaxf(ey2 - ey1, 0.0f);
    float enc = ew * eh;
    float giou = iou - __fdividef(enc - uni, enc + EPS);
    s_giou += fmaxf(1.0f - giou, 0.0f);

    // ---- weighted BCE ----
    float cl = r.cl, ct = r.ct;
    float bce = fmaxf(cl, 0.0f) - cl * ct + __logf(1.0f + __expf(-fabsf(cl)));
    float w = ((ct == 1.0f) && (cl < 0.0f)) ? FN_PENALTY : 1.0f;  // sigmoid<0.5 <=> logit<0
    s_cut += bce * w;
}

__device__ __forceinline__ void block_reduce_store(
    float s_class, float s_bbox, float s_giou, float s_cut,
    float4* __restrict__ out_slot)
{
    s_class = waveReduceSum(s_class);
    s_bbox  = waveReduceSum(s_bbox);
    s_giou  = waveReduceSum(s_giou);
    s_cut   = waveReduceSum(s_cut);

    __shared__ float red[4][4];
    const int lane = threadIdx.x & 63;
    const int wave = threadIdx.x >> 6;
    if (lane == 0) {
        red[wave][0] = s_class;
        red[wave][1] = s_bbox;
        red[wave][2] = s_giou;
        red[wave][3] = s_cut;
    }
    __syncthreads();
    if (threadIdx.x == 0) {
        float4 r;
        r.x = red[0][0] + red[1][0] + red[2][0] + red[3][0];
        r.y = red[0][1] + red[1][1] + red[2][1] + red[3][1];
        r.z = red[0][2] + red[1][2] + red[2][2] + red[3][2];
        r.w = red[0][3] + red[1][3] + red[2][3] + red[3][3];
        *out_slot = r;
    }
}

// Stage 1: persistent blocks, software-pipelined grid-stride loop.
// Loads for row j+1 are in flight while computing row j — memory issue
// never idles; reduce tail paid once per block (amortized over ~8 rows).
__global__ __launch_bounds__(BLOCK, 8) void loss_reduce(
    const float4* __restrict__ pred_logits,
    const int*    __restrict__ labels,
    const float4* __restrict__ pred_boxes,
    const float4* __restrict__ target_boxes,
    const float*  __restrict__ cut_logits,
    const float*  __restrict__ cut_targets,
    float4* __restrict__ block_out, int n)
{
    float s_class = 0.0f, s_bbox = 0.0f, s_giou = 0.0f, s_cut = 0.0f;
    const int stride = gridDim.x * BLOCK;
    int i = blockIdx.x * BLOCK + threadIdx.x;

    if (i < n) {
        Row cur = load_row(pred_logits, labels, pred_boxes, target_boxes,
                           cut_logits, cut_targets, i);
        int nx = i + stride;
        while (nx < n) {
            Row nxt = load_row(pred_logits, labels, pred_boxes, target_boxes,
                               cut_logits, cut_targets, nx);   // issue loads
            accum_row(cur, s_class, s_bbox, s_giou, s_cut);    // overlap compute
            cur = nxt;                                         // rotate (waitcnt here)
            nx += stride;
        }
        accum_row(cur, s_class, s_bbox, s_giou, s_cut);
    }

    block_reduce_store(s_class, s_bbox, s_giou, s_cut, &block_out[blockIdx.x]);
}

// Stage 2: reduce stage-1 partials -> gridDim partials.
__global__ __launch_bounds__(BLOCK) void reduce_partials(
    const float4* __restrict__ in, int n, float4* __restrict__ out)
{
    float c = 0.0f, b = 0.0f, g = 0.0f, u = 0.0f;
    for (int i = blockIdx.x * BLOCK + threadIdx.x; i < n; i += gridDim.x * BLOCK) {
        float4 r = in[i];
        c += r.x; b += r.y; g += r.z; u += r.w;
    }
    block_reduce_store(c, b, g, u, &out[blockIdx.x]);
}

// Stage 3: one wave reduces stage-2 partials, writes the 5 outputs.
__global__ void finalize_kernel(const float4* __restrict__ in, int n,
                                float* __restrict__ out, float inv_n)
{
    const int lane = threadIdx.x & 63;
    float c = 0.0f, b = 0.0f, g = 0.0f, u = 0.0f;
    for (int i = lane; i < n; i += 64) {
        float4 r = in[i];
        c += r.x; b += r.y; g += r.z; u += r.w;
    }
    c = waveReduceSum(c);
    b = waveReduceSum(b);
    g = waveReduceSum(g);
    u = waveReduceSum(u);
    if (lane == 0) {
        float lc   = fmaxf(c * inv_n, 0.0f);
        float lb   = fmaxf(b * inv_n * 0.25f, 0.0f);  // mean over 4N elems
        float lg   = fmaxf(g * inv_n, 0.0f);
        float lcut = fmaxf(u * inv_n, 0.0f);
        float total = 1.0f * lc + 5.0f * lb + 2.0f * lg + 3.0f * lcut;
        out[0] = total;
        out[1] = lc;
        out[2] = lb;
        out[3] = lg;
        out[4] = lcut;
    }
}

extern "C" void kernel_launch(void* const* d_in, const int* in_sizes, int n_in,
                              void* d_out, int out_size, void* d_ws, size_t ws_size,
                              hipStream_t stream) {
    const float4* pred_logits  = (const float4*)d_in[0];
    const int*    labels       = (const int*)d_in[1];
    const float4* pred_boxes   = (const float4*)d_in[2];
    const float4* target_boxes = (const float4*)d_in[3];
    const float*  cut_logits   = (const float*)d_in[4];
    const float*  cut_targets  = (const float*)d_in[5];
    float4* ws4 = (float4*)d_ws;
    float*  out = (float*)d_out;
    const int n = in_sizes[1];  // rows

    // 2048 persistent blocks = 8 blocks/CU (VGPR<=64 via launch_bounds):
    // every block resident for the whole kernel, ~8 rows/thread pipelined.
    const int grid1 = 2048;
    const int grid2 = 64;
    float4* part1 = ws4;                 // grid1 entries
    float4* part2 = ws4 + grid1;         // grid2 entries

    loss_reduce<<<grid1, BLOCK, 0, stream>>>(pred_logits, labels, pred_boxes,
                                             target_boxes, cut_logits, cut_targets,
                                             part1, n);
    reduce_partials<<<grid2, BLOCK, 0, stream>>>(part1, grid1, part2);
    finalize_kernel<<<1, 64, 0, stream>>>(part2, grid2, out, 1.0f / (float)n);
}

// Round 6
// 236.264 us; speedup vs baseline: 1.0074x; 1.0074x over previous
//
#include <hip/hip_runtime.h>
#include <math.h>

#define EPS 1e-7f
#define FN_PENALTY 10.0f
#define BLOCK 256

// Stream-split: block ranges sized proportional to bytes read so roles finish together.
// boxes 128 MB : focal 80 MB : cut 32 MB  ->  2176 : 1376 : 544 of 4096 blocks.
#define GRID1    4096
#define NB_BOX   2176
#define NB_FOCAL 1376
#define NB_CUT   544

__device__ __forceinline__ float waveReduceSum(float v) {
    #pragma unroll
    for (int off = 32; off > 0; off >>= 1)
        v += __shfl_down(v, off, 64);
    return v;
}

__device__ __forceinline__ float4 validate_fix(float4 b) {
    bool invalid = (b.x > b.z) || (b.y > b.w);
    if (invalid) {
        b.x = fmaxf(b.x, 0.0f);
        b.y = fmaxf(b.y, 0.0f);
        b.z = fmaxf(b.z, 0.0f);
        b.w = fmaxf(b.w, 0.0f);
    }
    b.z = fmaxf(b.z, b.x + 1e-6f);
    b.w = fmaxf(b.w, b.y + 1e-6f);
    return b;
}

__device__ __forceinline__ float bce_term(float cl, float ct) {
    float bce = fmaxf(cl, 0.0f) - cl * ct + __logf(1.0f + __expf(-fabsf(cl)));
    float w = ((ct == 1.0f) && (cl < 0.0f)) ? FN_PENALTY : 1.0f;  // sigmoid<0.5 <=> logit<0
    return bce * w;
}

__device__ __forceinline__ void block_reduce_store(
    float s_class, float s_bbox, float s_giou, float s_cut,
    float4* __restrict__ out_slot)
{
    s_class = waveReduceSum(s_class);
    s_bbox  = waveReduceSum(s_bbox);
    s_giou  = waveReduceSum(s_giou);
    s_cut   = waveReduceSum(s_cut);

    __shared__ float red[4][4];
    const int lane = threadIdx.x & 63;
    const int wave = threadIdx.x >> 6;
    if (lane == 0) {
        red[wave][0] = s_class;
        red[wave][1] = s_bbox;
        red[wave][2] = s_giou;
        red[wave][3] = s_cut;
    }
    __syncthreads();
    if (threadIdx.x == 0) {
        float4 r;
        r.x = red[0][0] + red[1][0] + red[2][0] + red[3][0];
        r.y = red[0][1] + red[1][1] + red[2][1] + red[3][1];
        r.z = red[0][2] + red[1][2] + red[2][2] + red[3][2];
        r.w = red[0][3] + red[1][3] + red[2][3] + red[3][3];
        *out_slot = r;
    }
}

// Stage 1: stream-specialized blocks. Each role touches only its own input
// arrays -> per-CU access pattern is 1-2 contiguous streams (copy-kernel
// shape) instead of 6 interleaved streams.
__global__ __launch_bounds__(BLOCK) void loss_reduce(
    const float4* __restrict__ pred_logits,
    const int*    __restrict__ labels,
    const float4* __restrict__ pred_boxes,
    const float4* __restrict__ target_boxes,
    const float*  __restrict__ cut_logits,
    const float*  __restrict__ cut_targets,
    float4* __restrict__ block_out, int n)
{
    const int b = blockIdx.x;
    float s_class = 0.0f, s_bbox = 0.0f, s_giou = 0.0f, s_cut = 0.0f;

    if (b < NB_BOX) {
        // ---- boxes role: bbox L1 + GIoU (reads pred_boxes, target_boxes) ----
        const int stride = NB_BOX * BLOCK;
        for (int i = b * BLOCK + threadIdx.x; i < n; i += stride) {
            float4 pb = pred_boxes[i];
            float4 tb = target_boxes[i];

            s_bbox += fabsf(pb.x - tb.x) + fabsf(pb.y - tb.y)
                    + fabsf(pb.z - tb.z) + fabsf(pb.w - tb.w);

            float4 b1 = validate_fix(pb);
            float4 b2 = validate_fix(tb);
            float area1 = (b1.z - b1.x) * (b1.w - b1.y);
            float area2 = (b2.z - b2.x) * (b2.w - b2.y);
            float ltx = fmaxf(b1.x, b2.x), lty = fmaxf(b1.y, b2.y);
            float rbx = fminf(b1.z, b2.z), rby = fminf(b1.w, b2.w);
            float iw = fmaxf(rbx - ltx, 0.0f), ih = fmaxf(rby - lty, 0.0f);
            float inter = iw * ih;
            float uni = area1 + area2 - inter;
            float iou = __fdividef(inter, uni + EPS);
            float ex1 = fminf(b1.x, b2.x), ey1 = fminf(b1.y, b2.y);
            float ex2 = fmaxf(b1.z, b2.z), ey2 = fmaxf(b1.w, b2.w);
            float ew = fmaxf(ex2 - ex1, 0.0f), eh = fmaxf(ey2 - ey1, 0.0f);
            float enc = ew * eh;
            float giou = iou - __fdividef(enc - uni, enc + EPS);
            s_giou += fmaxf(1.0f - giou, 0.0f);
        }
    } else if (b < NB_BOX + NB_FOCAL) {
        // ---- focal role: class loss (reads pred_logits, labels) ----
        const int stride = NB_FOCAL * BLOCK;
        for (int i = (b - NB_BOX) * BLOCK + threadIdx.x; i < n; i += stride) {
            float4 lg = pred_logits[i];
            int lbl = labels[i] & 3;
            float l0 = lg.x, l1 = lg.y, l2 = lg.z, l3 = lg.w;
            float m = fmaxf(fmaxf(l0, l1), fmaxf(l2, l3));
            float e0 = __expf(l0 - m), e1 = __expf(l1 - m),
                  e2 = __expf(l2 - m), e3 = __expf(l3 - m);
            float se = e0 + e1 + e2 + e3;
            float lsel = (lbl == 0) ? l0 : (lbl == 1) ? l1 : (lbl == 2) ? l2 : l3;
            float ce = __logf(se) + m - lsel;   // lse - lsel
            float pt = __expf(-ce);
            float om = 1.0f - pt;
            s_class += om * om * ce;            // ALPHA=1, GAMMA=2
        }
    } else {
        // ---- cut role: weighted BCE (reads cut_logits, cut_targets), 4 rows/float4 ----
        const int stride = NB_CUT * BLOCK;
        const int n4 = n >> 2;
        const float4* cl4 = (const float4*)cut_logits;
        const float4* ct4 = (const float4*)cut_targets;
        int t = (b - NB_BOX - NB_FOCAL) * BLOCK + threadIdx.x;
        for (int i = t; i < n4; i += stride) {
            float4 a = cl4[i];
            float4 c = ct4[i];
            s_cut += bce_term(a.x, c.x) + bce_term(a.y, c.y)
                   + bce_term(a.z, c.z) + bce_term(a.w, c.w);
        }
        if (t == 0) {  // tail rows if n not divisible by 4
            for (int i = n4 << 2; i < n; ++i)
                s_cut += bce_term(cut_logits[i], cut_targets[i]);
        }
    }

    block_reduce_store(s_class, s_bbox, s_giou, s_cut, &block_out[blockIdx.x]);
}

// Stage 2: reduce stage-1 partials -> gridDim partials.
__global__ __launch_bounds__(BLOCK) void reduce_partials(
    const float4* __restrict__ in, int n, float4* __restrict__ out)
{
    float c = 0.0f, b = 0.0f, g = 0.0f, u = 0.0f;
    for (int i = blockIdx.x * BLOCK + threadIdx.x; i < n; i += gridDim.x * BLOCK) {
        float4 r = in[i];
        c += r.x; b += r.y; g += r.z; u += r.w;
    }
    block_reduce_store(c, b, g, u, &out[blockIdx.x]);
}

// Stage 3: one wave reduces stage-2 partials, writes the 5 outputs.
__global__ void finalize_kernel(const float4* __restrict__ in, int n,
                                float* __restrict__ out, float inv_n)
{
    const int lane = threadIdx.x & 63;
    float c = 0.0f, b = 0.0f, g = 0.0f, u = 0.0f;
    for (int i = lane; i < n; i += 64) {
        float4 r = in[i];
        c += r.x; b += r.y; g += r.z; u += r.w;
    }
    c = waveReduceSum(c);
    b = waveReduceSum(b);
    g = waveReduceSum(g);
    u = waveReduceSum(u);
    if (lane == 0) {
        float lc   = fmaxf(c * inv_n, 0.0f);
        float lb   = fmaxf(b * inv_n * 0.25f, 0.0f);  // mean over 4N elems
        float lg   = fmaxf(g * inv_n, 0.0f);
        float lcut = fmaxf(u * inv_n, 0.0f);
        float total = 1.0f * lc + 5.0f * lb + 2.0f * lg + 3.0f * lcut;
        out[0] = total;
        out[1] = lc;
        out[2] = lb;
        out[3] = lg;
        out[4] = lcut;
    }
}

extern "C" void kernel_launch(void* const* d_in, const int* in_sizes, int n_in,
                              void* d_out, int out_size, void* d_ws, size_t ws_size,
                              hipStream_t stream) {
    const float4* pred_logits  = (const float4*)d_in[0];
    const int*    labels       = (const int*)d_in[1];
    const float4* pred_boxes   = (const float4*)d_in[2];
    const float4* target_boxes = (const float4*)d_in[3];
    const float*  cut_logits   = (const float*)d_in[4];
    const float*  cut_targets  = (const float*)d_in[5];
    float4* ws4 = (float4*)d_ws;
    float*  out = (float*)d_out;
    const int n = in_sizes[1];  // rows

    const int grid2 = 64;
    float4* part1 = ws4;                 // GRID1 entries (64 KB)
    float4* part2 = ws4 + GRID1;         // grid2 entries

    loss_reduce<<<GRID1, BLOCK, 0, stream>>>(pred_logits, labels, pred_boxes,
                                             target_boxes, cut_logits, cut_targets,
                                             part1, n);
    reduce_partials<<<grid2, BLOCK, 0, stream>>>(part1, GRID1, part2);
    finalize_kernel<<<1, 64, 0, stream>>>(part2, grid2, out, 1.0f / (float)n);
}

// Round 7
// 217.601 us; speedup vs baseline: 1.0938x; 1.0858x over previous
//
#include <hip/hip_runtime.h>
#include <math.h>

#define EPS 1e-7f
#define FN_PENALTY 10.0f
#define BLOCK 256

typedef float  vf4 __attribute__((ext_vector_type(4)));
typedef int    vi4 __attribute__((ext_vector_type(4)));

// Non-temporal 16-B load: global_load_dwordx4 with nt — bypasses L1 allocation.
__device__ __forceinline__ float4 ntload4f(const float4* p) {
    vf4 v = __builtin_nontemporal_load((const vf4*)p);
    float4 r; r.x = v.x; r.y = v.y; r.z = v.z; r.w = v.w;
    return r;
}
__device__ __forceinline__ int ntloadi(const int* p) {
    return __builtin_nontemporal_load(p);
}
__device__ __forceinline__ float ntloadf(const float* p) {
    return __builtin_nontemporal_load(p);
}

__device__ __forceinline__ float waveReduceSum(float v) {
    #pragma unroll
    for (int off = 32; off > 0; off >>= 1)
        v += __shfl_down(v, off, 64);
    return v;
}

__device__ __forceinline__ float4 validate_fix(float4 b) {
    bool invalid = (b.x > b.z) || (b.y > b.w);
    if (invalid) {
        b.x = fmaxf(b.x, 0.0f);
        b.y = fmaxf(b.y, 0.0f);
        b.z = fmaxf(b.z, 0.0f);
        b.w = fmaxf(b.w, 0.0f);
    }
    b.z = fmaxf(b.z, b.x + 1e-6f);
    b.w = fmaxf(b.w, b.y + 1e-6f);
    return b;
}

__device__ __forceinline__ void accum_row(
    float4 lg, int lbl, float4 pb, float4 tb, float cl, float ct,
    float& s_class, float& s_bbox, float& s_giou, float& s_cut)
{
    // ---- focal class loss ----
    float l0 = lg.x, l1 = lg.y, l2 = lg.z, l3 = lg.w;
    float m = fmaxf(fmaxf(l0, l1), fmaxf(l2, l3));
    float e0 = __expf(l0 - m), e1 = __expf(l1 - m),
          e2 = __expf(l2 - m), e3 = __expf(l3 - m);
    float se = e0 + e1 + e2 + e3;
    lbl &= 3;
    float lsel = (lbl == 0) ? l0 : (lbl == 1) ? l1 : (lbl == 2) ? l2 : l3;
    float ce = __logf(se) + m - lsel;  // lse - lsel
    float pt = __expf(-ce);
    float om = 1.0f - pt;
    s_class += om * om * ce;           // ALPHA=1, GAMMA=2

    // ---- bbox L1 ----
    s_bbox += fabsf(pb.x - tb.x) + fabsf(pb.y - tb.y)
            + fabsf(pb.z - tb.z) + fabsf(pb.w - tb.w);

    // ---- GIoU ----
    float4 b1 = validate_fix(pb);
    float4 b2 = validate_fix(tb);
    float area1 = (b1.z - b1.x) * (b1.w - b1.y);
    float area2 = (b2.z - b2.x) * (b2.w - b2.y);
    float ltx = fmaxf(b1.x, b2.x), lty = fmaxf(b1.y, b2.y);
    float rbx = fminf(b1.z, b2.z), rby = fminf(b1.w, b2.w);
    float iw = fmaxf(rbx - ltx, 0.0f), ih = fmaxf(rby - lty, 0.0f);
    float inter = iw * ih;
    float uni = area1 + area2 - inter;
    float iou = __fdividef(inter, uni + EPS);
    float ex1 = fminf(b1.x, b2.x), ey1 = fminf(b1.y, b2.y);
    float ex2 = fmaxf(b1.z, b2.z), ey2 = fmaxf(b1.w, b2.w);
    float ew = fmaxf(ex2 - ex1, 0.0f), eh = fmaxf(ey2 - ey1, 0.0f);
    float enc = ew * eh;
    float giou = iou - __fdividef(enc - uni, enc + EPS);
    s_giou += fmaxf(1.0f - giou, 0.0f);

    // ---- weighted BCE ----
    float bce = fmaxf(cl, 0.0f) - cl * ct + __logf(1.0f + __expf(-fabsf(cl)));
    float w = ((ct == 1.0f) && (cl < 0.0f)) ? FN_PENALTY : 1.0f;  // sigmoid<0.5 <=> logit<0
    s_cut += bce * w;
}

__device__ __forceinline__ void block_reduce_store(
    float s_class, float s_bbox, float s_giou, float s_cut,
    float4* __restrict__ out_slot)
{
    s_class = waveReduceSum(s_class);
    s_bbox  = waveReduceSum(s_bbox);
    s_giou  = waveReduceSum(s_giou);
    s_cut   = waveReduceSum(s_cut);

    __shared__ float red[4][4];
    const int lane = threadIdx.x & 63;
    const int wave = threadIdx.x >> 6;
    if (lane == 0) {
        red[wave][0] = s_class;
        red[wave][1] = s_bbox;
        red[wave][2] = s_giou;
        red[wave][3] = s_cut;
    }
    __syncthreads();
    if (threadIdx.x == 0) {
        float4 r;
        r.x = red[0][0] + red[1][0] + red[2][0] + red[3][0];
        r.y = red[0][1] + red[1][1] + red[2][1] + red[3][1];
        r.z = red[0][2] + red[1][2] + red[2][2] + red[3][2];
        r.w = red[0][3] + red[1][3] + red[2][3] + red[3][3];
        *out_slot = r;
    }
}

// Stage 1: grid-stride, 2 rows per iteration, ALL loads non-temporal.
// 12 nt loads issued before the dependent compute of either row.
__global__ __launch_bounds__(BLOCK) void loss_reduce(
    const float4* __restrict__ pred_logits,
    const int*    __restrict__ labels,
    const float4* __restrict__ pred_boxes,
    const float4* __restrict__ target_boxes,
    const float*  __restrict__ cut_logits,
    const float*  __restrict__ cut_targets,
    float4* __restrict__ block_out, int n)
{
    float s_class = 0.0f, s_bbox = 0.0f, s_giou = 0.0f, s_cut = 0.0f;
    const int stride  = gridDim.x * BLOCK;
    const int stride2 = stride * 2;
    int i = blockIdx.x * BLOCK + threadIdx.x;

    for (; i + stride < n; i += stride2) {
        const int j = i + stride;
        // issue all 12 loads (nt) before any dependent use
        float4 lgA = ntload4f(&pred_logits[i]);
        float4 lgB = ntload4f(&pred_logits[j]);
        float4 pbA = ntload4f(&pred_boxes[i]);
        float4 pbB = ntload4f(&pred_boxes[j]);
        float4 tbA = ntload4f(&target_boxes[i]);
        float4 tbB = ntload4f(&target_boxes[j]);
        int    lbA = ntloadi(&labels[i]);
        int    lbB = ntloadi(&labels[j]);
        float  clA = ntloadf(&cut_logits[i]);
        float  clB = ntloadf(&cut_logits[j]);
        float  ctA = ntloadf(&cut_targets[i]);
        float  ctB = ntloadf(&cut_targets[j]);

        accum_row(lgA, lbA, pbA, tbA, clA, ctA, s_class, s_bbox, s_giou, s_cut);
        accum_row(lgB, lbB, pbB, tbB, clB, ctB, s_class, s_bbox, s_giou, s_cut);
    }
    if (i < n) {
        accum_row(ntload4f(&pred_logits[i]), ntloadi(&labels[i]),
                  ntload4f(&pred_boxes[i]), ntload4f(&target_boxes[i]),
                  ntloadf(&cut_logits[i]), ntloadf(&cut_targets[i]),
                  s_class, s_bbox, s_giou, s_cut);
    }

    block_reduce_store(s_class, s_bbox, s_giou, s_cut, &block_out[blockIdx.x]);
}

// Stage 2: reduce stage-1 partials -> gridDim partials.
__global__ __launch_bounds__(BLOCK) void reduce_partials(
    const float4* __restrict__ in, int n, float4* __restrict__ out)
{
    float c = 0.0f, b = 0.0f, g = 0.0f, u = 0.0f;
    for (int i = blockIdx.x * BLOCK + threadIdx.x; i < n; i += gridDim.x * BLOCK) {
        float4 r = in[i];
        c += r.x; b += r.y; g += r.z; u += r.w;
    }
    block_reduce_store(c, b, g, u, &out[blockIdx.x]);
}

// Stage 3: one wave reduces stage-2 partials, writes the 5 outputs.
__global__ void finalize_kernel(const float4* __restrict__ in, int n,
                                float* __restrict__ out, float inv_n)
{
    const int lane = threadIdx.x & 63;
    float c = 0.0f, b = 0.0f, g = 0.0f, u = 0.0f;
    for (int i = lane; i < n; i += 64) {
        float4 r = in[i];
        c += r.x; b += r.y; g += r.z; u += r.w;
    }
    c = waveReduceSum(c);
    b = waveReduceSum(b);
    g = waveReduceSum(g);
    u = waveReduceSum(u);
    if (lane == 0) {
        float lc   = fmaxf(c * inv_n, 0.0f);
        float lb   = fmaxf(b * inv_n * 0.25f, 0.0f);  // mean over 4N elems
        float lg   = fmaxf(g * inv_n, 0.0f);
        float lcut = fmaxf(u * inv_n, 0.0f);
        float total = 1.0f * lc + 5.0f * lb + 2.0f * lg + 3.0f * lcut;
        out[0] = total;
        out[1] = lc;
        out[2] = lb;
        out[3] = lg;
        out[4] = lcut;
    }
}

extern "C" void kernel_launch(void* const* d_in, const int* in_sizes, int n_in,
                              void* d_out, int out_size, void* d_ws, size_t ws_size,
                              hipStream_t stream) {
    const float4* pred_logits  = (const float4*)d_in[0];
    const int*    labels       = (const int*)d_in[1];
    const float4* pred_boxes   = (const float4*)d_in[2];
    const float4* target_boxes = (const float4*)d_in[3];
    const float*  cut_logits   = (const float*)d_in[4];
    const float*  cut_targets  = (const float*)d_in[5];
    float4* ws4 = (float4*)d_ws;
    float*  out = (float*)d_out;
    const int n = in_sizes[1];  // rows

    const int grid1 = 2048;   // 8 blocks/CU, 8 rows/thread (4 unrolled x2 iters)
    const int grid2 = 64;
    float4* part1 = ws4;                 // grid1 entries
    float4* part2 = ws4 + grid1;         // grid2 entries

    loss_reduce<<<grid1, BLOCK, 0, stream>>>(pred_logits, labels, pred_boxes,
                                             target_boxes, cut_logits, cut_targets,
                                             part1, n);
    reduce_partials<<<grid2, BLOCK, 0, stream>>>(part1, grid1, part2);
    finalize_kernel<<<1, 64, 0, stream>>>(part2, grid2, out, 1.0f / (float)n);
}